// Round 11
// baseline (256.864 us; speedup 1.0000x reference)
//
#include <hip/hip_runtime.h>
#include <math.h>

// Problem constants
#define BATCH 4
#define HH 56
#define WW 56
#define DMODEL 256
#define NHEADS 8
#define HD 32
#define NNB 49               // 7x7 neighborhood
#define NTOK (BATCH*HH*WW)   // 12544

#define HALO 22              // 16 + 2*3
#define NHTOK (HALO*HALO)    // 484
// KV_PAD must keep rows 16B-aligned for ds_*_b128: stride (bf16) must be a
// multiple of 8. 40 (80B) aligned & proven; 36 broke b128 codegen (R9, 3.5x).
#define KV_PAD 40

typedef __attribute__((ext_vector_type(8))) short s16x8;
typedef __attribute__((ext_vector_type(4))) float f32x4;

__device__ inline unsigned short f2b(float f) {
    union { float f; unsigned int u; } v; v.f = f;
    unsigned int r = v.u + 0x7FFF + ((v.u >> 16) & 1);  // RNE
    return (unsigned short)(r >> 16);
}
__device__ inline float b2f(unsigned short u) {
    union { float f; unsigned int u; } v; v.u = ((unsigned int)u) << 16;
    return v.f;
}

// async 16B/lane global->LDS copy; lds base wave-uniform, lane i -> base+i*16
__device__ __forceinline__ void async16(const unsigned short* g, unsigned short* l) {
    __builtin_amdgcn_global_load_lds(
        (const __attribute__((address_space(1))) unsigned int*)g,
        (__attribute__((address_space(3))) unsigned int*)l, 16, 0, 0);
}

// ---------------------------------------------------------------------------
// prep: cast+transpose weights to [N][K] bf16.
// ---------------------------------------------------------------------------
__global__ __launch_bounds__(256)
void prep_kernel(const float* __restrict__ Wq, const float* __restrict__ Wp,
                 const float* __restrict__ W1, const float* __restrict__ W2,
                 unsigned short* __restrict__ Wqb, unsigned short* __restrict__ Wpb,
                 unsigned short* __restrict__ W1b, unsigned short* __restrict__ W2b)
{
    int i = blockIdx.x * 256 + threadIdx.x;
    if (i < 196608) {            // W_qkv: K=256, N=768
        int n = i >> 8, k = i & 255;
        Wqb[i] = f2b(Wq[k * 768 + n]);
    } else if ((i -= 196608) < 65536) {   // W_proj: K=256, N=256
        int n = i >> 8, k = i & 255;
        Wpb[i] = f2b(Wp[k * 256 + n]);
    } else if ((i -= 65536) < 262144) {   // W1: K=256, N=1024
        int n = i >> 8, k = i & 255;
        W1b[i] = f2b(W1[k * 1024 + n]);
    } else {                              // W2: K=1024, N=256
        i -= 262144;
        int n = i >> 10, k = i & 1023;
        W2b[i] = f2b(W2[k * 256 + n]);
    }
}

// ---------------------------------------------------------------------------
// bf16 MFMA GEMM (qkv): 128x128 tile, 4 waves; A = f32 x with fused cast.
// ---------------------------------------------------------------------------
template<int BN, bool AF32>
__global__ __launch_bounds__(256)
void gemm_k(const unsigned short* __restrict__ Ab, const float* __restrict__ Af,
            const unsigned short* __restrict__ Bt, const float* __restrict__ bias,
            float* __restrict__ outf, unsigned short* __restrict__ outb,
            int M, int N, int K, int relu)
{
    constexpr int NB  = BN / 32;
    constexpr int BPW = BN / 32;
    __shared__ unsigned short As[128 * 64];
    __shared__ unsigned short Bs[BN * 64];

    const int tid = threadIdx.x;
    const int bm = blockIdx.y * 128, bn = blockIdx.x * BN;
    const int wid = tid >> 6, lane = tid & 63;
    const int wm = (wid >> 1) * 64, wn = (wid & 1) * (BN / 2);
    const int row16 = lane & 15, quad = lane >> 4;
    const int crow = lane >> 3, ck8 = (lane & 7) * 8;

    f32x4 acc[4][NB] = {};

    for (int k0 = 0; k0 < K; k0 += 64) {
        float4 fv[8];
        if (AF32) {
            const float* g = Af + (size_t)(bm + (tid >> 1)) * K + k0 + (tid & 1) * 32;
            #pragma unroll
            for (int u = 0; u < 8; ++u) fv[u] = *(const float4*)(g + u * 4);
        }
        __syncthreads();
        if (AF32) {
            unsigned short* d = As + (tid >> 1) * 64 + (tid & 1) * 32;
            #pragma unroll
            for (int u = 0; u < 4; ++u) {
                s16x8 o;
                o[0] = (short)f2b(fv[2*u].x);   o[1] = (short)f2b(fv[2*u].y);
                o[2] = (short)f2b(fv[2*u].z);   o[3] = (short)f2b(fv[2*u].w);
                o[4] = (short)f2b(fv[2*u+1].x); o[5] = (short)f2b(fv[2*u+1].y);
                o[6] = (short)f2b(fv[2*u+1].z); o[7] = (short)f2b(fv[2*u+1].w);
                *(s16x8*)(d + u * 8) = o;
            }
        } else {
            #pragma unroll
            for (int c = 0; c < 4; ++c) {
                const int ch = wid * 4 + c;
                async16(Ab + (size_t)(bm + ch * 8 + crow) * K + k0 + ck8, As + ch * 512);
            }
        }
        #pragma unroll
        for (int c = 0; c < BPW; ++c) {
            const int ch = wid * BPW + c;
            async16(Bt + (size_t)(bn + ch * 8 + crow) * K + k0 + ck8, Bs + ch * 512);
        }
        __syncthreads();

        #pragma unroll
        for (int kc = 0; kc < 2; ++kc) {
            s16x8 af[4], bf[NB];
            #pragma unroll
            for (int i = 0; i < 4; ++i)
                af[i] = *(const s16x8*)(As + (wm + i * 16 + row16) * 64 + kc * 32 + quad * 8);
            #pragma unroll
            for (int j = 0; j < NB; ++j)
                bf[j] = *(const s16x8*)(Bs + (wn + j * 16 + row16) * 64 + kc * 32 + quad * 8);
            #pragma unroll
            for (int i = 0; i < 4; ++i)
                #pragma unroll
                for (int j = 0; j < NB; ++j)
                    acc[i][j] = __builtin_amdgcn_mfma_f32_16x16x32_bf16(af[i], bf[j], acc[i][j], 0, 0, 0);
        }
    }

    #pragma unroll
    for (int j = 0; j < NB; ++j) {
        const int col = bn + wn + j * 16 + row16;
        const float bb = bias[col];
        #pragma unroll
        for (int i = 0; i < 4; ++i) {
            const int r0 = bm + wm + i * 16 + quad * 4;
            #pragma unroll
            for (int reg = 0; reg < 4; ++reg) {
                float v = acc[i][j][reg] + bb;
                if (relu) v = fmaxf(v, 0.f);
                if (outf) outf[(size_t)(r0 + reg) * N + col] = v;
                if (outb) outb[(size_t)(r0 + reg) * N + col] = f2b(v);
            }
        }
    }
}

// ---------------------------------------------------------------------------
// Fused GEMM (N=256 full-row) + residual add + LayerNorm (attention side).
// Tile 32 rows x 256 cols, grid M/32 = 392, 4 waves (wave = 64 cols).
// ---------------------------------------------------------------------------
__global__ __launch_bounds__(256)
void gemm_ln(const unsigned short* __restrict__ Ab, const unsigned short* __restrict__ Bt,
             const float* __restrict__ bias, const float* __restrict__ resid,
             const float* __restrict__ g, const float* __restrict__ beta,
             float* __restrict__ outf, unsigned short* __restrict__ outb, int K)
{
    __shared__ unsigned short As[32 * 64];    // 4 KB (reused for LN reduction)
    __shared__ unsigned short Bs[256 * 64];   // 32 KB

    const int tid = threadIdx.x;
    const int bm = blockIdx.x * 32;
    const int wid = tid >> 6, lane = tid & 63;
    const int wn = wid * 64;
    const int row16 = lane & 15, quad = lane >> 4;
    const int crow = lane >> 3, ck8 = (lane & 7) * 8;

    f32x4 acc[2][4] = {};

    for (int k0 = 0; k0 < K; k0 += 64) {
        __syncthreads();
        #pragma unroll
        for (int c = 0; c < 9; ++c) {
            const int ch = wid * 9 + c;
            if (ch < 4) {
                async16(Ab + (size_t)(bm + ch * 8 + crow) * K + k0 + ck8, As + ch * 512);
            } else {
                const int bc = ch - 4;
                async16(Bt + (size_t)(bc * 8 + crow) * K + k0 + ck8, Bs + bc * 512);
            }
        }
        __syncthreads();

        #pragma unroll
        for (int kc = 0; kc < 2; ++kc) {
            s16x8 af[2], bf[4];
            #pragma unroll
            for (int i = 0; i < 2; ++i)
                af[i] = *(const s16x8*)(As + (i * 16 + row16) * 64 + kc * 32 + quad * 8);
            #pragma unroll
            for (int j = 0; j < 4; ++j)
                bf[j] = *(const s16x8*)(Bs + (wn + j * 16 + row16) * 64 + kc * 32 + quad * 8);
            #pragma unroll
            for (int i = 0; i < 2; ++i)
                #pragma unroll
                for (int j = 0; j < 4; ++j)
                    acc[i][j] = __builtin_amdgcn_mfma_f32_16x16x32_bf16(af[i], bf[j], acc[i][j], 0, 0, 0);
        }
    }

    float bb[4], gv[4], bev[4];
    #pragma unroll
    for (int j = 0; j < 4; ++j) {
        const int col = wn + j * 16 + row16;
        bb[j] = bias[col]; gv[j] = g[col]; bev[j] = beta[col];
    }
    #pragma unroll
    for (int i = 0; i < 2; ++i) {
        #pragma unroll
        for (int reg = 0; reg < 4; ++reg) {
            const size_t rb = (size_t)(bm + i * 16 + quad * 4 + reg) * 256;
            #pragma unroll
            for (int j = 0; j < 4; ++j)
                acc[i][j][reg] += bb[j] + resid[rb + wn + j * 16 + row16];
        }
    }

    __syncthreads();
    float* red = (float*)As;              // [32][4][2]
    #pragma unroll
    for (int i = 0; i < 2; ++i) {
        #pragma unroll
        for (int reg = 0; reg < 4; ++reg) {
            float s1 = 0.f, s2 = 0.f;
            #pragma unroll
            for (int j = 0; j < 4; ++j) {
                const float t = acc[i][j][reg];
                s1 += t; s2 += t * t;
            }
            #pragma unroll
            for (int o = 1; o < 16; o <<= 1) {
                s1 += __shfl_xor(s1, o, 64);
                s2 += __shfl_xor(s2, o, 64);
            }
            if (row16 == 0) {
                const int lrow = i * 16 + quad * 4 + reg;
                red[lrow * 8 + wid * 2]     = s1;
                red[lrow * 8 + wid * 2 + 1] = s2;
            }
        }
    }
    __syncthreads();
    float* stats = red + 256;             // [32][2]
    if (tid < 32) {
        const float S1 = red[tid*8] + red[tid*8+2] + red[tid*8+4] + red[tid*8+6];
        const float S2 = red[tid*8+1] + red[tid*8+3] + red[tid*8+5] + red[tid*8+7];
        const float m = S1 * (1.0f / 256.0f);
        const float var = S2 * (1.0f / 256.0f) - m * m;
        stats[tid * 2]     = m;
        stats[tid * 2 + 1] = rsqrtf(var + 1e-5f);
    }
    __syncthreads();

    #pragma unroll
    for (int i = 0; i < 2; ++i) {
        #pragma unroll
        for (int reg = 0; reg < 4; ++reg) {
            const int lrow = i * 16 + quad * 4 + reg;
            const float m = stats[lrow * 2], r = stats[lrow * 2 + 1];
            const size_t rb = (size_t)(bm + lrow) * 256;
            #pragma unroll
            for (int j = 0; j < 4; ++j) {
                const int col = wn + j * 16 + row16;
                const float o = (acc[i][j][reg] - m) * r * gv[j] + bev[j];
                outf[rb + col] = o;
                if (outb) outb[rb + col] = f2b(o);
            }
        }
    }
}

// ---------------------------------------------------------------------------
// Fully fused FFN + LN:  out = LN(xn + relu(xn@W1+b1)@W2 + b2)*g + beta.
// Block = 16 token rows, grid M/16 = 784. LDS 74 KB -> 2 blocks/CU.
// Loop over 16 ff-chunks of 64: phase1 h_chunk(16x64) via MFMA (xn resident
// in LDS, W1 chunk streamed), relu+bias, h_chunk -> LDS (C-layout->A-layout
// transform), phase2 f(16x256) += h_chunk @ W2_chunk. h never hits global.
// ---------------------------------------------------------------------------
__global__ __launch_bounds__(256)
void ffn_ln(const unsigned short* __restrict__ xnb, const unsigned short* __restrict__ W1b,
            const float* __restrict__ b1, const unsigned short* __restrict__ W2b,
            const float* __restrict__ b2, const float* __restrict__ resid,
            const float* __restrict__ g, const float* __restrict__ beta,
            float* __restrict__ outf)
{
    __shared__ unsigned short As[16 * 256];    // 8 KB  xn rows [r][k]
    __shared__ unsigned short W1s[64 * 256];   // 32 KB [ff][k] chunk
    __shared__ unsigned short W2s[256 * 64];   // 32 KB [n][kff] chunk
    __shared__ unsigned short hs[16 * 64];     // 2 KB  [r][ff] (reused for LN red)

    const int tid = threadIdx.x;
    const int bm = blockIdx.x * 16;
    const int wid = tid >> 6, lane = tid & 63;
    const int row16 = lane & 15, quad = lane >> 4;
    const int wn = wid * 64;                   // phase-2 col range

    // stage xn rows once: 8 KB = 8 wave-ops (2/wave); op ch covers rows [2ch,2ch+2)
    #pragma unroll
    for (int c = 0; c < 2; ++c) {
        const int ch = wid * 2 + c;
        const int r = 2 * ch + (lane >> 5);
        const int k = (lane & 31) * 8;
        async16(xnb + (size_t)(bm + r) * 256 + k, As + ch * 512);
    }

    f32x4 facc[4] = {};

    for (int c = 0; c < 16; ++c) {
        __syncthreads();   // prev chunk's W1s/W2s/hs reads complete
        // stage W1 chunk (ff rows [c*64, +64)): 32 ops, 8/wave
        #pragma unroll
        for (int o = 0; o < 8; ++o) {
            const int ch = wid * 8 + o;
            const int fr = 2 * ch + (lane >> 5);
            const int k = (lane & 31) * 8;
            async16(W1b + (size_t)(c * 64 + fr) * 256 + k, W1s + ch * 512);
        }
        // stage W2 chunk (k-slice [c*64,+64) of 256 n-rows): 32 ops, 8/wave
        #pragma unroll
        for (int o = 0; o < 8; ++o) {
            const int ch = wid * 8 + o;
            const int n = ch * 8 + (lane >> 3);
            const int ko = (lane & 7) * 8;
            async16(W2b + (size_t)n * 1024 + c * 64 + ko, W2s + ch * 512);
        }
        __syncthreads();   // staged data visible (drains As stage too on c==0)

        // phase 1: h_chunk = relu(xn @ W1chunk + b1); wave -> ff col-tile wid
        f32x4 a1 = {};
        #pragma unroll
        for (int ks = 0; ks < 8; ++ks) {
            s16x8 af = *(const s16x8*)(As + row16 * 256 + ks * 32 + quad * 8);
            s16x8 bf = *(const s16x8*)(W1s + (wid * 16 + row16) * 256 + ks * 32 + quad * 8);
            a1 = __builtin_amdgcn_mfma_f32_16x16x32_bf16(af, bf, a1, 0, 0, 0);
        }
        {
            const float bb = b1[c * 64 + wid * 16 + row16];
            #pragma unroll
            for (int reg = 0; reg < 4; ++reg) {   // C-layout: col=row16, row=quad*4+reg
                const float v = fmaxf(a1[reg] + bb, 0.f);
                hs[(quad * 4 + reg) * 64 + wid * 16 + row16] = f2b(v);
            }
        }
        __syncthreads();   // hs visible

        // phase 2: facc += h_chunk(16x64) @ W2chunk(64 kff x 256 n)
        #pragma unroll
        for (int ks = 0; ks < 2; ++ks) {
            s16x8 af = *(const s16x8*)(hs + row16 * 64 + ks * 32 + quad * 8);
            #pragma unroll
            for (int j = 0; j < 4; ++j) {
                s16x8 bf = *(const s16x8*)(W2s + (wn + j * 16 + row16) * 64 + ks * 32 + quad * 8);
                facc[j] = __builtin_amdgcn_mfma_f32_16x16x32_bf16(af, bf, facc[j], 0, 0, 0);
            }
        }
    }

    // ---- epilogue: bias + residual + LN (16 rows x 256 cols)
    float bb2[4], gv[4], bev[4];
    #pragma unroll
    for (int j = 0; j < 4; ++j) {
        const int col = wn + j * 16 + row16;
        bb2[j] = b2[col]; gv[j] = g[col]; bev[j] = beta[col];
    }
    #pragma unroll
    for (int reg = 0; reg < 4; ++reg) {
        const size_t rb = (size_t)(bm + quad * 4 + reg) * 256;
        #pragma unroll
        for (int j = 0; j < 4; ++j)
            facc[j][reg] += bb2[j] + resid[rb + wn + j * 16 + row16];
    }

    __syncthreads();                      // last chunk's hs reads done
    float* red = (float*)hs;              // [16][4][2] = 128 floats
    #pragma unroll
    for (int reg = 0; reg < 4; ++reg) {
        float s1 = 0.f, s2 = 0.f;
        #pragma unroll
        for (int j = 0; j < 4; ++j) {
            const float t = facc[j][reg];
            s1 += t; s2 += t * t;
        }
        #pragma unroll
        for (int o = 1; o < 16; o <<= 1) {
            s1 += __shfl_xor(s1, o, 64);
            s2 += __shfl_xor(s2, o, 64);
        }
        if (row16 == 0) {
            const int lrow = quad * 4 + reg;
            red[lrow * 8 + wid * 2]     = s1;
            red[lrow * 8 + wid * 2 + 1] = s2;
        }
    }
    __syncthreads();
    float* stats = red + 128;             // [16][2]
    if (tid < 16) {
        const float S1 = red[tid*8] + red[tid*8+2] + red[tid*8+4] + red[tid*8+6];
        const float S2 = red[tid*8+1] + red[tid*8+3] + red[tid*8+5] + red[tid*8+7];
        const float m = S1 * (1.0f / 256.0f);
        const float var = S2 * (1.0f / 256.0f) - m * m;
        stats[tid * 2]     = m;
        stats[tid * 2 + 1] = rsqrtf(var + 1e-5f);
    }
    __syncthreads();

    #pragma unroll
    for (int reg = 0; reg < 4; ++reg) {
        const int lrow = quad * 4 + reg;
        const float m = stats[lrow * 2], r = stats[lrow * 2 + 1];
        const size_t rb = (size_t)(bm + lrow) * 256;
        #pragma unroll
        for (int j = 0; j < 4; ++j) {
            const int col = wn + j * 16 + row16;
            outf[rb + col] = (facc[j][reg] - m) * r * gv[j] + bev[j];
        }
    }
}

// ---------------------------------------------------------------------------
// Tiled neighborhood attention (R6/R10 proven): block = (16x16 tile, head),
// 256 threads, 1 query/lane; K,V halo in LDS (pad 40, 16B-aligned rows);
// fused no-max softmax pass (state = qf[32]+acc[32], no spill).
// ---------------------------------------------------------------------------
__global__ __launch_bounds__(256, 2)
void natt_kernel(const unsigned short* __restrict__ qkvb, unsigned short* __restrict__ att)
{
    const int blk  = blockIdx.x;          // 4*16*8 = 512
    const int head = blk & 7;
    const int t2   = blk >> 3;
    const int tile = t2 & 15;
    const int b    = t2 >> 4;
    const int r0 = (tile >> 2) * 16, c0 = (tile & 3) * 16;
    const int hs = min(max(r0 - 3, 0), 34);
    const int ws = min(max(c0 - 3, 0), 34);

    __shared__ unsigned short Ks[NHTOK * KV_PAD];
    __shared__ unsigned short Vs[NHTOK * KV_PAD];

    const int tid = threadIdx.x;

    #pragma unroll
    for (int it = 0; it < 8; ++it) {
        const int t = it * 64 + (tid >> 2);
        if (t < NHTOK) {
            const int hr = t / HALO, hc = t - hr * HALO;
            const size_t rb = ((size_t)((b * 56 + hs + hr) * 56 + (ws + hc))) * 768;
            const int d8 = (tid & 3) * 8;
            *(s16x8*)(Ks + t * KV_PAD + d8) = *(const s16x8*)(qkvb + rb + 256 + head * 32 + d8);
            *(s16x8*)(Vs + t * KV_PAD + d8) = *(const s16x8*)(qkvb + rb + 512 + head * 32 + d8);
        }
    }

    const int qh = min(r0 + (tid >> 4), 55);
    const int qw = min(c0 + (tid & 15), 55);
    const int tok = (b * 56 + qh) * 56 + qw;
    const int ro = min(max(qh - 3, 0), 49) - hs;
    const int co = min(max(qw - 3, 0), 49) - ws;

    float qf[32];
    {
        const unsigned short* qp = qkvb + (size_t)tok * 768 + head * 32;
        #pragma unroll
        for (int c8 = 0; c8 < 4; ++c8) {
            s16x8 qv = *(const s16x8*)(qp + c8 * 8);
            #pragma unroll
            for (int e = 0; e < 8; ++e)
                qf[c8 * 8 + e] = b2f((unsigned short)qv[e]) * 0.17677669529663687f;
        }
    }
    __syncthreads();

    float acc[32] = {};
    float sum = 0.f;
    for (int i = 0; i < 7; ++i) {
        const int trow = (ro + i) * HALO + co;
        #pragma unroll
        for (int j = 0; j < 7; ++j) {
            const unsigned short* kp = Ks + (trow + j) * KV_PAD;
            const unsigned short* vp = Vs + (trow + j) * KV_PAD;
            s16x8 k0 = *(const s16x8*)(kp);
            s16x8 k1 = *(const s16x8*)(kp + 8);
            s16x8 k2 = *(const s16x8*)(kp + 16);
            s16x8 k3 = *(const s16x8*)(kp + 24);
            s16x8 v0 = *(const s16x8*)(vp);
            s16x8 v1 = *(const s16x8*)(vp + 8);
            s16x8 v2 = *(const s16x8*)(vp + 16);
            s16x8 v3 = *(const s16x8*)(vp + 24);
            float sc = 0.f;
            #pragma unroll
            for (int e = 0; e < 8; ++e) {
                sc = fmaf(qf[e],      b2f((unsigned short)k0[e]), sc);
                sc = fmaf(qf[8 + e],  b2f((unsigned short)k1[e]), sc);
                sc = fmaf(qf[16 + e], b2f((unsigned short)k2[e]), sc);
                sc = fmaf(qf[24 + e], b2f((unsigned short)k3[e]), sc);
            }
            const float p = __expf(sc);
            sum += p;
            #pragma unroll
            for (int e = 0; e < 8; ++e) {
                acc[e]      = fmaf(p, b2f((unsigned short)v0[e]), acc[e]);
                acc[8 + e]  = fmaf(p, b2f((unsigned short)v1[e]), acc[8 + e]);
                acc[16 + e] = fmaf(p, b2f((unsigned short)v2[e]), acc[16 + e]);
                acc[24 + e] = fmaf(p, b2f((unsigned short)v3[e]), acc[24 + e]);
            }
        }
    }
    const float inv = 1.0f / sum;

    unsigned short* op = att + (size_t)tok * DMODEL + head * 32;
    #pragma unroll
    for (int d4 = 0; d4 < 8; ++d4) {
        ushort4 o;
        o.x = f2b(acc[d4 * 4 + 0] * inv);
        o.y = f2b(acc[d4 * 4 + 1] * inv);
        o.z = f2b(acc[d4 * 4 + 2] * inv);
        o.w = f2b(acc[d4 * 4 + 3] * inv);
        *(ushort4*)(op + d4 * 4) = o;
    }
}

// ---------------------------------------------------------------------------
extern "C" void kernel_launch(void* const* d_in, const int* in_sizes, int n_in,
                              void* d_out, int out_size, void* d_ws, size_t ws_size,
                              hipStream_t stream)
{
    const float* x      = (const float*)d_in[0];
    const float* W_qkv  = (const float*)d_in[1];
    const float* b_qkv  = (const float*)d_in[2];
    const float* W_proj = (const float*)d_in[3];
    const float* b_proj = (const float*)d_in[4];
    const float* W1     = (const float*)d_in[5];
    const float* b1     = (const float*)d_in[6];
    const float* W2     = (const float*)d_in[7];
    const float* b2     = (const float*)d_in[8];
    const float* g1     = (const float*)d_in[9];
    const float* be1    = (const float*)d_in[10];
    const float* g2     = (const float*)d_in[11];
    const float* be2    = (const float*)d_in[12];
    float* out = (float*)d_out;

    char* ws = (char*)d_ws;
    const int M = NTOK;  // 12544

    unsigned short* qkvb = (unsigned short*)ws;                     // [M][768] bf16
    unsigned short* attb = (unsigned short*)(ws + 38535168);        // [M][256] bf16
    float*          xn   = (float*)(ws + 57802752);                 // [M][256] f32
    unsigned short* xnb  = (unsigned short*)(ws + 70647808);        // [M][256] bf16
    unsigned short* Wqb  = (unsigned short*)(ws + 77070336);
    unsigned short* Wpb  = Wqb + 196608;
    unsigned short* W1b  = Wpb + 65536;
    unsigned short* W2b  = W1b + 262144;

    dim3 blk(256);

    // 0) cast/transpose weights to bf16
    prep_kernel<<<dim3(3072), blk, 0, stream>>>(W_qkv, W_proj, W1, W2, Wqb, Wpb, W1b, W2b);

    // 1) qkvb = bf16(x @ W_qkv + b_qkv)   — A=f32 x, cast fused into staging
    gemm_k<128, true><<<dim3(6, 98), blk, 0, stream>>>(nullptr, x, Wqb, b_qkv, nullptr, qkvb, M, 768, 256, 0);

    // 2) tiled neighborhood attention -> attb
    natt_kernel<<<dim3(512), blk, 0, stream>>>(qkvb, attb);

    // 3) xn = LN(x + attb @ W_proj + b_proj)  (f32 + bf16), fused
    gemm_ln<<<dim3(M / 32), blk, 0, stream>>>(attb, Wpb, b_proj, x, g1, be1, xn, xnb, 256);

    // 4) out = LN(xn + relu(xnb@W1+b1)@W2 + b2) — whole FFN fused, h stays on-chip
    ffn_ln<<<dim3(M / 16), blk, 0, stream>>>(xnb, W1b, b1, W2b, b2, xn, g2, be2, out);
}

// Round 12
// 207.137 us; speedup vs baseline: 1.2401x; 1.2401x over previous
//
#include <hip/hip_runtime.h>
#include <math.h>

// Problem constants
#define BATCH 4
#define HH 56
#define WW 56
#define DMODEL 256
#define NHEADS 8
#define HD 32
#define NNB 49               // 7x7 neighborhood
#define NTOK (BATCH*HH*WW)   // 12544

#define HALO 22              // 16 + 2*3
#define NHTOK (HALO*HALO)    // 484
// KV_PAD must keep rows 16B-aligned for ds_*_b128: stride (bf16) must be a
// multiple of 8. 40 (80B) aligned & proven; 36 broke b128 codegen (R9, 3.5x).
#define KV_PAD 40

typedef __attribute__((ext_vector_type(8))) short s16x8;
typedef __attribute__((ext_vector_type(4))) float f32x4;

__device__ inline unsigned short f2b(float f) {
    union { float f; unsigned int u; } v; v.f = f;
    unsigned int r = v.u + 0x7FFF + ((v.u >> 16) & 1);  // RNE
    return (unsigned short)(r >> 16);
}
__device__ inline float b2f(unsigned short u) {
    union { float f; unsigned int u; } v; v.u = ((unsigned int)u) << 16;
    return v.f;
}

// async 16B/lane global->LDS copy; lds base wave-uniform, lane i -> base+i*16
__device__ __forceinline__ void async16(const unsigned short* g, unsigned short* l) {
    __builtin_amdgcn_global_load_lds(
        (const __attribute__((address_space(1))) unsigned int*)g,
        (__attribute__((address_space(3))) unsigned int*)l, 16, 0, 0);
}

// ---------------------------------------------------------------------------
// prep: cast+transpose weights to [N][K] bf16.
// ---------------------------------------------------------------------------
__global__ __launch_bounds__(256)
void prep_kernel(const float* __restrict__ Wq, const float* __restrict__ Wp,
                 const float* __restrict__ W1, const float* __restrict__ W2,
                 unsigned short* __restrict__ Wqb, unsigned short* __restrict__ Wpb,
                 unsigned short* __restrict__ W1b, unsigned short* __restrict__ W2b)
{
    int i = blockIdx.x * 256 + threadIdx.x;
    if (i < 196608) {            // W_qkv: K=256, N=768
        int n = i >> 8, k = i & 255;
        Wqb[i] = f2b(Wq[k * 768 + n]);
    } else if ((i -= 196608) < 65536) {   // W_proj: K=256, N=256
        int n = i >> 8, k = i & 255;
        Wpb[i] = f2b(Wp[k * 256 + n]);
    } else if ((i -= 65536) < 262144) {   // W1: K=256, N=1024
        int n = i >> 8, k = i & 255;
        W1b[i] = f2b(W1[k * 1024 + n]);
    } else {                              // W2: K=1024, N=256
        i -= 262144;
        int n = i >> 10, k = i & 1023;
        W2b[i] = f2b(W2[k * 256 + n]);
    }
}

// ---------------------------------------------------------------------------
// bf16 MFMA GEMM, m97-style staging. 128xBN tile (BN=128), 4 waves.
// A: bf16 [M][K] via global_load_lds, or f32 (AF32) with fused cast.
// B: bf16 [N][K] via global_load_lds. LDS unpadded [row][64] (m97 layout).
// ---------------------------------------------------------------------------
template<int BN, bool AF32>
__global__ __launch_bounds__(256)
void gemm_k(const unsigned short* __restrict__ Ab, const float* __restrict__ Af,
            const unsigned short* __restrict__ Bt, const float* __restrict__ bias,
            float* __restrict__ outf, unsigned short* __restrict__ outb,
            int M, int N, int K, int relu)
{
    constexpr int NB  = BN / 32;
    constexpr int BPW = BN / 32;
    __shared__ unsigned short As[128 * 64];
    __shared__ unsigned short Bs[BN * 64];

    const int tid = threadIdx.x;
    const int bm = blockIdx.y * 128, bn = blockIdx.x * BN;
    const int wid = tid >> 6, lane = tid & 63;
    const int wm = (wid >> 1) * 64, wn = (wid & 1) * (BN / 2);
    const int row16 = lane & 15, quad = lane >> 4;
    const int crow = lane >> 3, ck8 = (lane & 7) * 8;

    f32x4 acc[4][NB] = {};

    for (int k0 = 0; k0 < K; k0 += 64) {
        float4 fv[8];
        if (AF32) {
            const float* g = Af + (size_t)(bm + (tid >> 1)) * K + k0 + (tid & 1) * 32;
            #pragma unroll
            for (int u = 0; u < 8; ++u) fv[u] = *(const float4*)(g + u * 4);
        }
        __syncthreads();
        if (AF32) {
            unsigned short* d = As + (tid >> 1) * 64 + (tid & 1) * 32;
            #pragma unroll
            for (int u = 0; u < 4; ++u) {
                s16x8 o;
                o[0] = (short)f2b(fv[2*u].x);   o[1] = (short)f2b(fv[2*u].y);
                o[2] = (short)f2b(fv[2*u].z);   o[3] = (short)f2b(fv[2*u].w);
                o[4] = (short)f2b(fv[2*u+1].x); o[5] = (short)f2b(fv[2*u+1].y);
                o[6] = (short)f2b(fv[2*u+1].z); o[7] = (short)f2b(fv[2*u+1].w);
                *(s16x8*)(d + u * 8) = o;
            }
        } else {
            #pragma unroll
            for (int c = 0; c < 4; ++c) {
                const int ch = wid * 4 + c;
                async16(Ab + (size_t)(bm + ch * 8 + crow) * K + k0 + ck8, As + ch * 512);
            }
        }
        #pragma unroll
        for (int c = 0; c < BPW; ++c) {
            const int ch = wid * BPW + c;
            async16(Bt + (size_t)(bn + ch * 8 + crow) * K + k0 + ck8, Bs + ch * 512);
        }
        __syncthreads();

        #pragma unroll
        for (int kc = 0; kc < 2; ++kc) {
            s16x8 af[4], bf[NB];
            #pragma unroll
            for (int i = 0; i < 4; ++i)
                af[i] = *(const s16x8*)(As + (wm + i * 16 + row16) * 64 + kc * 32 + quad * 8);
            #pragma unroll
            for (int j = 0; j < NB; ++j)
                bf[j] = *(const s16x8*)(Bs + (wn + j * 16 + row16) * 64 + kc * 32 + quad * 8);
            #pragma unroll
            for (int i = 0; i < 4; ++i)
                #pragma unroll
                for (int j = 0; j < NB; ++j)
                    acc[i][j] = __builtin_amdgcn_mfma_f32_16x16x32_bf16(af[i], bf[j], acc[i][j], 0, 0, 0);
        }
    }

    #pragma unroll
    for (int j = 0; j < NB; ++j) {
        const int col = bn + wn + j * 16 + row16;
        const float bb = bias[col];
        #pragma unroll
        for (int i = 0; i < 4; ++i) {
            const int r0 = bm + wm + i * 16 + quad * 4;
            #pragma unroll
            for (int reg = 0; reg < 4; ++reg) {
                float v = acc[i][j][reg] + bb;
                if (relu) v = fmaxf(v, 0.f);
                if (outf) outf[(size_t)(r0 + reg) * N + col] = v;
                if (outb) outb[(size_t)(r0 + reg) * N + col] = f2b(v);
            }
        }
    }
}

// ---------------------------------------------------------------------------
// Fused GEMM (N=256 full-row tile) + residual add + LayerNorm.
// out = LN(resid + A@Bt^T + bias) * g + beta.
// Tile 32 rows x 256 cols (grid M/32 = 392 >= 256 CUs), 4 waves; wave w
// covers cols [64w, 64w+64), all 32 rows.
// ---------------------------------------------------------------------------
__global__ __launch_bounds__(256)
void gemm_ln(const unsigned short* __restrict__ Ab, const unsigned short* __restrict__ Bt,
             const float* __restrict__ bias, const float* __restrict__ resid,
             const float* __restrict__ g, const float* __restrict__ beta,
             float* __restrict__ outf, unsigned short* __restrict__ outb, int K)
{
    __shared__ unsigned short As[32 * 64];    // 4 KB (reused for LN reduction)
    __shared__ unsigned short Bs[256 * 64];   // 32 KB

    const int tid = threadIdx.x;
    const int bm = blockIdx.x * 32;
    const int wid = tid >> 6, lane = tid & 63;
    const int wn = wid * 64;
    const int row16 = lane & 15, quad = lane >> 4;
    const int crow = lane >> 3, ck8 = (lane & 7) * 8;

    f32x4 acc[2][4] = {};

    for (int k0 = 0; k0 < K; k0 += 64) {
        __syncthreads();
        // 36 chunks: 4 A (32 rows) + 32 B (256 rows); 9 per wave
        #pragma unroll
        for (int c = 0; c < 9; ++c) {
            const int ch = wid * 9 + c;
            if (ch < 4) {
                async16(Ab + (size_t)(bm + ch * 8 + crow) * K + k0 + ck8, As + ch * 512);
            } else {
                const int bc = ch - 4;
                async16(Bt + (size_t)(bc * 8 + crow) * K + k0 + ck8, Bs + bc * 512);
            }
        }
        __syncthreads();

        #pragma unroll
        for (int kc = 0; kc < 2; ++kc) {
            s16x8 af[2], bf[4];
            #pragma unroll
            for (int i = 0; i < 2; ++i)
                af[i] = *(const s16x8*)(As + (i * 16 + row16) * 64 + kc * 32 + quad * 8);
            #pragma unroll
            for (int j = 0; j < 4; ++j)
                bf[j] = *(const s16x8*)(Bs + (wn + j * 16 + row16) * 64 + kc * 32 + quad * 8);
            #pragma unroll
            for (int i = 0; i < 2; ++i)
                #pragma unroll
                for (int j = 0; j < 4; ++j)
                    acc[i][j] = __builtin_amdgcn_mfma_f32_16x16x32_bf16(af[i], bf[j], acc[i][j], 0, 0, 0);
        }
    }

    // ---- epilogue: bias + residual, in-register
    float bb[4], gv[4], bev[4];
    #pragma unroll
    for (int j = 0; j < 4; ++j) {
        const int col = wn + j * 16 + row16;
        bb[j] = bias[col]; gv[j] = g[col]; bev[j] = beta[col];
    }
    #pragma unroll
    for (int i = 0; i < 2; ++i) {
        #pragma unroll
        for (int reg = 0; reg < 4; ++reg) {
            const size_t rb = (size_t)(bm + i * 16 + quad * 4 + reg) * 256;
            #pragma unroll
            for (int j = 0; j < 4; ++j)
                acc[i][j][reg] += bb[j] + resid[rb + wn + j * 16 + row16];
        }
    }

    // ---- per-row sum / sumsq: reduce across row16 (16 lanes), then LDS
    __syncthreads();                      // all MFMA reads of As done
    float* red = (float*)As;              // [32 rows][4 waves][2]
    #pragma unroll
    for (int i = 0; i < 2; ++i) {
        #pragma unroll
        for (int reg = 0; reg < 4; ++reg) {
            float s1 = 0.f, s2 = 0.f;
            #pragma unroll
            for (int j = 0; j < 4; ++j) {
                const float t = acc[i][j][reg];
                s1 += t; s2 += t * t;
            }
            #pragma unroll
            for (int o = 1; o < 16; o <<= 1) {
                s1 += __shfl_xor(s1, o, 64);
                s2 += __shfl_xor(s2, o, 64);
            }
            if (row16 == 0) {
                const int lrow = i * 16 + quad * 4 + reg;
                red[lrow * 8 + wid * 2]     = s1;
                red[lrow * 8 + wid * 2 + 1] = s2;
            }
        }
    }
    __syncthreads();
    float* stats = red + 256;             // [32][2] = m, invstd
    if (tid < 32) {
        const float S1 = red[tid*8] + red[tid*8+2] + red[tid*8+4] + red[tid*8+6];
        const float S2 = red[tid*8+1] + red[tid*8+3] + red[tid*8+5] + red[tid*8+7];
        const float m = S1 * (1.0f / 256.0f);
        const float var = S2 * (1.0f / 256.0f) - m * m;
        stats[tid * 2]     = m;
        stats[tid * 2 + 1] = rsqrtf(var + 1e-5f);
    }
    __syncthreads();

    // ---- normalize + store
    #pragma unroll
    for (int i = 0; i < 2; ++i) {
        #pragma unroll
        for (int reg = 0; reg < 4; ++reg) {
            const int lrow = i * 16 + quad * 4 + reg;
            const float m = stats[lrow * 2], r = stats[lrow * 2 + 1];
            const size_t rb = (size_t)(bm + lrow) * 256;
            #pragma unroll
            for (int j = 0; j < 4; ++j) {
                const int col = wn + j * 16 + row16;
                const float o = (acc[i][j][reg] - m) * r * gv[j] + bev[j];
                outf[rb + col] = o;
                if (outb) outb[rb + col] = f2b(o);
            }
        }
    }
}

// ---------------------------------------------------------------------------
// Tiled neighborhood attention (R6/R10 proven): block = (16x16 tile, head),
// 256 threads, 1 query/lane; K,V halo in LDS (pad 40, 16B-aligned rows);
// fused no-max softmax pass (state = qf[32]+acc[32], no spill).
// ---------------------------------------------------------------------------
__global__ __launch_bounds__(256, 2)
void natt_kernel(const unsigned short* __restrict__ qkvb, unsigned short* __restrict__ att)
{
    const int blk  = blockIdx.x;          // 4*16*8 = 512
    const int head = blk & 7;
    const int t2   = blk >> 3;
    const int tile = t2 & 15;
    const int b    = t2 >> 4;
    const int r0 = (tile >> 2) * 16, c0 = (tile & 3) * 16;
    const int hs = min(max(r0 - 3, 0), 34);
    const int ws = min(max(c0 - 3, 0), 34);

    __shared__ unsigned short Ks[NHTOK * KV_PAD];
    __shared__ unsigned short Vs[NHTOK * KV_PAD];

    const int tid = threadIdx.x;

    #pragma unroll
    for (int it = 0; it < 8; ++it) {
        const int t = it * 64 + (tid >> 2);
        if (t < NHTOK) {
            const int hr = t / HALO, hc = t - hr * HALO;
            const size_t rb = ((size_t)((b * 56 + hs + hr) * 56 + (ws + hc))) * 768;
            const int d8 = (tid & 3) * 8;
            *(s16x8*)(Ks + t * KV_PAD + d8) = *(const s16x8*)(qkvb + rb + 256 + head * 32 + d8);
            *(s16x8*)(Vs + t * KV_PAD + d8) = *(const s16x8*)(qkvb + rb + 512 + head * 32 + d8);
        }
    }

    const int qh = min(r0 + (tid >> 4), 55);
    const int qw = min(c0 + (tid & 15), 55);
    const int tok = (b * 56 + qh) * 56 + qw;
    const int ro = min(max(qh - 3, 0), 49) - hs;
    const int co = min(max(qw - 3, 0), 49) - ws;

    float qf[32];
    {
        const unsigned short* qp = qkvb + (size_t)tok * 768 + head * 32;
        #pragma unroll
        for (int c8 = 0; c8 < 4; ++c8) {
            s16x8 qv = *(const s16x8*)(qp + c8 * 8);
            #pragma unroll
            for (int e = 0; e < 8; ++e)
                qf[c8 * 8 + e] = b2f((unsigned short)qv[e]) * 0.17677669529663687f;
        }
    }
    __syncthreads();

    float acc[32] = {};
    float sum = 0.f;
    for (int i = 0; i < 7; ++i) {
        const int trow = (ro + i) * HALO + co;
        #pragma unroll
        for (int j = 0; j < 7; ++j) {
            const unsigned short* kp = Ks + (trow + j) * KV_PAD;
            const unsigned short* vp = Vs + (trow + j) * KV_PAD;
            s16x8 k0 = *(const s16x8*)(kp);
            s16x8 k1 = *(const s16x8*)(kp + 8);
            s16x8 k2 = *(const s16x8*)(kp + 16);
            s16x8 k3 = *(const s16x8*)(kp + 24);
            s16x8 v0 = *(const s16x8*)(vp);
            s16x8 v1 = *(const s16x8*)(vp + 8);
            s16x8 v2 = *(const s16x8*)(vp + 16);
            s16x8 v3 = *(const s16x8*)(vp + 24);
            float sc = 0.f;
            #pragma unroll
            for (int e = 0; e < 8; ++e) {
                sc = fmaf(qf[e],      b2f((unsigned short)k0[e]), sc);
                sc = fmaf(qf[8 + e],  b2f((unsigned short)k1[e]), sc);
                sc = fmaf(qf[16 + e], b2f((unsigned short)k2[e]), sc);
                sc = fmaf(qf[24 + e], b2f((unsigned short)k3[e]), sc);
            }
            const float p = __expf(sc);
            sum += p;
            #pragma unroll
            for (int e = 0; e < 8; ++e) {
                acc[e]      = fmaf(p, b2f((unsigned short)v0[e]), acc[e]);
                acc[8 + e]  = fmaf(p, b2f((unsigned short)v1[e]), acc[8 + e]);
                acc[16 + e] = fmaf(p, b2f((unsigned short)v2[e]), acc[16 + e]);
                acc[24 + e] = fmaf(p, b2f((unsigned short)v3[e]), acc[24 + e]);
            }
        }
    }
    const float inv = 1.0f / sum;

    unsigned short* op = att + (size_t)tok * DMODEL + head * 32;
    #pragma unroll
    for (int d4 = 0; d4 < 8; ++d4) {
        ushort4 o;
        o.x = f2b(acc[d4 * 4 + 0] * inv);
        o.y = f2b(acc[d4 * 4 + 1] * inv);
        o.z = f2b(acc[d4 * 4 + 2] * inv);
        o.w = f2b(acc[d4 * 4 + 3] * inv);
        *(ushort4*)(op + d4 * 4) = o;
    }
}

// ---------------------------------------------------------------------------
extern "C" void kernel_launch(void* const* d_in, const int* in_sizes, int n_in,
                              void* d_out, int out_size, void* d_ws, size_t ws_size,
                              hipStream_t stream)
{
    const float* x      = (const float*)d_in[0];
    const float* W_qkv  = (const float*)d_in[1];
    const float* b_qkv  = (const float*)d_in[2];
    const float* W_proj = (const float*)d_in[3];
    const float* b_proj = (const float*)d_in[4];
    const float* W1     = (const float*)d_in[5];
    const float* b1     = (const float*)d_in[6];
    const float* W2     = (const float*)d_in[7];
    const float* b2     = (const float*)d_in[8];
    const float* g1     = (const float*)d_in[9];
    const float* be1    = (const float*)d_in[10];
    const float* g2     = (const float*)d_in[11];
    const float* be2    = (const float*)d_in[12];
    float* out = (float*)d_out;

    char* ws = (char*)d_ws;
    const int M = NTOK;  // 12544

    unsigned short* qkvb = (unsigned short*)ws;                     // [M][768] bf16
    unsigned short* h    = (unsigned short*)ws;                     // [M][1024] bf16 (after qkvb dead)
    unsigned short* attb = (unsigned short*)(ws + 38535168);        // [M][256] bf16
    float*          xn   = (float*)(ws + 57802752);                 // [M][256] f32
    unsigned short* xnb  = (unsigned short*)(ws + 70647808);        // [M][256] bf16
    unsigned short* Wqb  = (unsigned short*)(ws + 77070336);
    unsigned short* Wpb  = Wqb + 196608;
    unsigned short* W1b  = Wpb + 65536;
    unsigned short* W2b  = W1b + 262144;

    dim3 blk(256);

    // 0) cast/transpose weights to bf16
    prep_kernel<<<dim3(3072), blk, 0, stream>>>(W_qkv, W_proj, W1, W2, Wqb, Wpb, W1b, W2b);

    // 1) qkvb = bf16(x @ W_qkv + b_qkv)   — A=f32 x, cast fused into staging
    gemm_k<128, true><<<dim3(6, 98), blk, 0, stream>>>(nullptr, x, Wqb, b_qkv, nullptr, qkvb, M, 768, 256, 0);

    // 2) tiled neighborhood attention -> attb
    natt_kernel<<<dim3(512), blk, 0, stream>>>(qkvb, attb);

    // 3+4) xn = LN(x + attb @ W_proj + b_proj)  (f32 + bf16), fused
    gemm_ln<<<dim3(M / 32), blk, 0, stream>>>(attb, Wpb, b_proj, x, g1, be1, xn, xnb, 256);

    // 5) h = relu(xnb @ W1 + b1)  (bf16)
    gemm_k<128, false><<<dim3(8, 98), blk, 0, stream>>>(xnb, nullptr, W1b, b1, nullptr, h, M, 1024, 256, 1);

    // 6+7) out = LN(xn + h @ W2 + b2), fused
    gemm_ln<<<dim3(M / 32), blk, 0, stream>>>(h, W2b, b2, xn, g2, be2, out, nullptr, 1024);
}